// Round 18
// baseline (237.092 us; speedup 1.0000x reference)
//
#include <hip/hip_runtime.h>
#include <math.h>

#define B_ 8
#define N_ 20000
#define K_ 128
#define C_ 256

static_assert(N_ % 32 == 0, "N must be multiple of 32");

constexpr float LMBDA = 100.0f;
constexpr float EPS_EV = 1e-10f;

typedef unsigned int u32x4 __attribute__((ext_vector_type(4)));
typedef short short8_t __attribute__((ext_vector_type(8)));
typedef float f32x4 __attribute__((ext_vector_type(4)));

// Split two fp32 into bf16 hi-plane (truncation; residual exact) and
// bf16 lo-plane (RNE of residual). Packed as (x1|x0) u32 words.
static __device__ inline void split2(float x0, float x1, unsigned& h, unsigned& l) {
  unsigned u0 = __builtin_bit_cast(unsigned, x0);
  unsigned u1 = __builtin_bit_cast(unsigned, x1);
  h = __builtin_amdgcn_perm(u1, u0, 0x07060302u);  // top16(x1)<<16 | top16(x0)
  float r0 = x0 - __builtin_bit_cast(float, u0 & 0xFFFF0000u);  // exact
  float r1 = x1 - __builtin_bit_cast(float, u1 & 0xFFFF0000u);  // exact
  unsigned v0 = __builtin_bit_cast(unsigned, r0);
  unsigned v1 = __builtin_bit_cast(unsigned, r1);
  v0 += 0x7FFFu + ((v0 >> 16) & 1u);  // RNE to bf16
  v1 += 0x7FFFu + ((v1 >> 16) & 1u);
  l = __builtin_amdgcn_perm(v1, v0, 0x07060302u);
}

// publish LDS writes + retire LDS reads, then raw barrier (global prefetch
// loads stay in flight across it -- no vmcnt drain).
#define KFENCE()                                              \
  do {                                                        \
    asm volatile("s_waitcnt lgkmcnt(0)" ::: "memory");        \
    __builtin_amdgcn_sched_barrier(0);                        \
    __builtin_amdgcn_s_barrier();                             \
    __builtin_amdgcn_sched_barrier(0);                        \
  } while (0)

// ---------------------------------------------------------------------------
// Kernel 1: projection GEMM, bf16x3 split MFMA (round-15/16/17: 128x128 tile,
// fragment-linear LDS -> zero bank conflicts, KFENCE 2-phase, XCD grid).
// ---------------------------------------------------------------------------
__global__ __launch_bounds__(512, 4)
void proj_mfma(const float* __restrict__ feat_x, const float* __restrict__ feat_y,
               const float* __restrict__ evx, const float* __restrict__ evy,
               float* __restrict__ part, int Sa, int chunk) {
  const int bm = blockIdx.z;
  const int b = bm >> 1, mat = bm & 1;
  const float* __restrict__ E = (mat ? evy : evx) + (size_t)b * K_ * N_;
  const float* __restrict__ F = (mat ? feat_y : feat_x) + (size_t)b * N_ * C_;
  const int c0 = blockIdx.y << 7;          // y = c-block (swizzled)
  const int s = blockIdx.x;                // x = slab
  const int nb = s * chunk;
  const int ne = min(N_, nb + chunk);
  const int nt = (ne - nb) >> 5;

  // 64KB: buf p at p*8192 u32; planes: Ah +0, Al +2048, Bh +4096, Bl +6144
  __shared__ unsigned int LDSU[16384];

  const int t = threadIdx.x;
  const int lane = t & 63, wv = t >> 6;
  const int wm = wv & 3;          // m-tile 0..3 (32 rows each)
  const int wcc = wv >> 2;        // c-half 0..1 (64 cols each)
  const int lr = lane & 15, lg = lane >> 4;

  // staging maps (slot t, fragment-linear)
  const int rA = ((t >> 7) << 5) | (((t >> 6) & 1) << 4) | (t & 15);
  const int oA = (t >> 4) & 3;
  const int cB = ((t >> 6) << 4) | (t & 15);
  const int oB = (t >> 4) & 3;

  const float* __restrict__ eb = E + (size_t)rA * N_ + (oA << 3);
  const float* __restrict__ fb = F + (size_t)(oB << 3) * C_ + c0 + cB;

  f32x4 acc[2][4];
#pragma unroll
  for (int i = 0; i < 2; ++i)
#pragma unroll
    for (int j = 0; j < 4; ++j) acc[i][j] = (f32x4){0.f, 0.f, 0.f, 0.f};

  struct Stage { float4 a0, a1; float b0, b1, b2, b3, b4, b5, b6, b7; };

  auto LOAD = [&](Stage& st, int n0) {
    const float* ep = eb + n0;
    st.a0 = *(const float4*)ep;
    st.a1 = *(const float4*)(ep + 4);
    const float* fp = fb + (size_t)n0 * C_;
    st.b0 = fp[0];
    st.b1 = fp[C_];
    st.b2 = fp[2 * C_];
    st.b3 = fp[3 * C_];
    st.b4 = fp[4 * C_];
    st.b5 = fp[5 * C_];
    st.b6 = fp[6 * C_];
    st.b7 = fp[7 * C_];
  };

  auto WRITE = [&](Stage& st, int p) {
    const int base = (p << 13) + (t << 2);
    unsigned h0, l0, h1, l1, h2, l2, h3, l3;
    split2(st.a0.x, st.a0.y, h0, l0);
    split2(st.a0.z, st.a0.w, h1, l1);
    split2(st.a1.x, st.a1.y, h2, l2);
    split2(st.a1.z, st.a1.w, h3, l3);
    *(u32x4*)&LDSU[base]        = (u32x4){h0, h1, h2, h3};
    *(u32x4*)&LDSU[base + 2048] = (u32x4){l0, l1, l2, l3};
    split2(st.b0, st.b1, h0, l0);
    split2(st.b2, st.b3, h1, l1);
    split2(st.b4, st.b5, h2, l2);
    split2(st.b6, st.b7, h3, l3);
    *(u32x4*)&LDSU[base + 4096] = (u32x4){h0, h1, h2, h3};
    *(u32x4*)&LDSU[base + 6144] = (u32x4){l0, l1, l2, l3};
  };

  auto COMPUTE = [&](int p) {
    const int pb = p << 13;
    short8_t a_h[2], a_l[2];
#pragma unroll
    for (int mt = 0; mt < 2; ++mt) {
      const int as = pb + (((wm << 1) + mt) << 8) + (lane << 2);
      a_h[mt] = *(const short8_t*)&LDSU[as];
      a_l[mt] = *(const short8_t*)&LDSU[as + 2048];
    }
#pragma unroll
    for (int ct = 0; ct < 4; ++ct) {
      const int ctg = (wcc << 2) + ct;
      const int bs = pb + 4096 + (ctg << 8) + (lane << 2);
      const short8_t b_h = *(const short8_t*)&LDSU[bs];
      const short8_t b_l = *(const short8_t*)&LDSU[bs + 2048];
#pragma unroll
      for (int mt = 0; mt < 2; ++mt) {
        acc[mt][ct] = __builtin_amdgcn_mfma_f32_16x16x32_bf16(a_h[mt], b_h, acc[mt][ct], 0, 0, 0);
        acc[mt][ct] = __builtin_amdgcn_mfma_f32_16x16x32_bf16(a_l[mt], b_h, acc[mt][ct], 0, 0, 0);
        acc[mt][ct] = __builtin_amdgcn_mfma_f32_16x16x32_bf16(a_h[mt], b_l, acc[mt][ct], 0, 0, 0);
      }
    }
  };

  Stage sA, sB;
  LOAD(sA, nb);                       // tile 0
  if (nt > 1) LOAD(sB, nb + 32);      // tile 1
  WRITE(sA, 0);                       // waits only tile-0 loads
  KFENCE();

  for (int it = 0; it < nt; it += 2) {
    if (it + 1 < nt) WRITE(sB, 1);                    // vmcnt wait: tile it+1
    if (it + 2 < nt) LOAD(sA, nb + ((it + 2) << 5));  // issued AFTER the wait
    COMPUTE(0);
    KFENCE();
    if (it + 1 < nt) {
      if (it + 2 < nt) WRITE(sA, 0);
      if (it + 3 < nt) LOAD(sB, nb + ((it + 3) << 5));
      COMPUTE(1);
      KFENCE();
    }
  }

  // epilogue: C/D layout col=lane&15, row=(lane>>4)*4+r
  float* __restrict__ P = part + ((size_t)bm * Sa + s) * (K_ * C_);
#pragma unroll
  for (int mt = 0; mt < 2; ++mt)
#pragma unroll
    for (int ct = 0; ct < 4; ++ct) {
      const int ccol = c0 + (wcc << 6) + (ct << 4) + lr;
#pragma unroll
      for (int r = 0; r < 4; ++r) {
        const int mrow = (wm << 5) + (mt << 4) + (lg << 2) + r;
        P[(size_t)mrow * C_ + ccol] = acc[mt][ct][r];
      }
    }
}

// ---------------------------------------------------------------------------
// Kernel 2: reduce split-n partials -> AB (float4 vectorized)
// ---------------------------------------------------------------------------
__global__ void reduce_parts(const float* __restrict__ part, float* __restrict__ AB, int Sa) {
  const int idx4 = blockIdx.x * 256 + threadIdx.x;       // float4 units
  if (idx4 >= 16 * K_ * C_ / 4) return;
  const int per = K_ * C_ / 4;
  const int bm = idx4 / per;
  const int rem4 = idx4 - bm * per;
  float4 v = {0.f, 0.f, 0.f, 0.f};
  for (int s = 0; s < Sa; ++s) {
    const float4 p = *(const float4*)&part[((size_t)bm * Sa + s) * (K_ * C_) + rem4 * 4];
    v.x += p.x; v.y += p.y; v.z += p.z; v.w += p.w;
  }
  *(float4*)&AB[(size_t)idx4 * 4] = v;
}

// ---------------------------------------------------------------------------
// Kernel 3: gram matrices, 64x64 quadrant per block (8 x 2 x 4 grid).
// which=0: Sm = A A^T + 1e-8 I ; which=1: Rm = Bm A^T
// ---------------------------------------------------------------------------
__global__ __launch_bounds__(256)
void gram_kernel(const float* __restrict__ AB, float* __restrict__ Sm, float* __restrict__ Rm) {
  const int b = blockIdx.x, which = blockIdx.y, qz = blockIdx.z;
  const int iq = (qz & 1) << 6, jq = (qz >> 1) << 6;
  const float* __restrict__ L  = AB + ((size_t)(b * 2 + which)) * (K_ * C_);
  const float* __restrict__ Ar = AB + ((size_t)(b * 2)) * (K_ * C_);
  float* __restrict__ out = (which ? Rm : Sm) + (size_t)b * (K_ * K_);
  const int t = threadIdx.x;
  const int ir = iq + ((t >> 4) << 2), jc = jq + ((t & 15) << 2);
  float acc[4][4] = {};
  for (int c0 = 0; c0 < C_; c0 += 4) {
    float4 li[4], rj[4];
#pragma unroll
    for (int i = 0; i < 4; ++i) li[i] = *(const float4*)(L + (size_t)(ir + i) * C_ + c0);
#pragma unroll
    for (int j = 0; j < 4; ++j) rj[j] = *(const float4*)(Ar + (size_t)(jc + j) * C_ + c0);
#pragma unroll
    for (int i = 0; i < 4; ++i)
#pragma unroll
      for (int j = 0; j < 4; ++j)
        acc[i][j] += li[i].x * rj[j].x + li[i].y * rj[j].y +
                     li[i].z * rj[j].z + li[i].w * rj[j].w;
  }
#pragma unroll
  for (int i = 0; i < 4; ++i)
#pragma unroll
    for (int j = 0; j < 4; ++j) {
      float v = acc[i][j];
      if (!which && (ir + i) == (jc + j)) v += 1e-8f;
      out[(size_t)(ir + i) * K_ + (jc + j)] = v;
    }
}

// ---------------------------------------------------------------------------
// Kernel 4: FUSED mask-prep + blocked Gauss-Jordan inverse, 512 threads
// (8 waves -- halves barrier-arrival spread vs round-17's 16 waves at
// 1 block/CU; ph2/ph3 use round-5's measured-passing 512-thread indexing).
// ---------------------------------------------------------------------------
__global__ __launch_bounds__(512)
void gjm_fused(const float* __restrict__ Sm, const float* __restrict__ evx,
               const float* __restrict__ evy, float* __restrict__ Sinv,
               float* __restrict__ PQ) {
  const int b = blockIdx.x, t = threadIdx.x;
  __shared__ float a[K_ * 132];    // S -> Sinv
  __shared__ float Tl[8192];       // gj scratch: Pi@0, Rp@512, Cp@4096
  __shared__ float ev[256];
  __shared__ float wmax[2];

  // ---- mask prep (threads 0..127), writes PQ global ----
  if (t < 128) {
    float e1 = evx[b * K_ + t];
    float e2 = evy[b * K_ + t];
    if (e1 != e1) e1 = EPS_EV;
    if (e2 != e2) e2 = EPS_EV;
    e1 = fminf(fmaxf(e1, EPS_EV), 1e6f);
    e2 = fminf(fmaxf(e2, EPS_EV), 1e6f);
    float v = fmaxf(e1, e2);
#pragma unroll
    for (int d = 1; d < 64; d <<= 1) v = fmaxf(v, __shfl_xor(v, d, 64));
    if ((t & 63) == 0) wmax[t >> 6] = v;
    ev[t] = e1; ev[128 + t] = e2;
  }
  __syncthreads();
  if (t < 128) {
    const float scale = fmaxf(fmaxf(wmax[0], wmax[1]), 1e-10f);
    const float g1 = sqrtf(ev[t] / scale);
    const float g2 = sqrtf(ev[128 + t] / scale);
    const float d1 = fmaf(g1, g1, 1.f);
    const float d2 = fmaf(g2, g2, 1.f);
    float* P = PQ + b * 512;
    P[t]       = g1 / d1;
    P[128 + t] = 1.f / d1;
    P[256 + t] = g2 / d2;
    P[384 + t] = 1.f / d2;
  }

  // ---- load S ----
  const float* __restrict__ Sb = Sm + (size_t)b * (K_ * K_);
#pragma unroll
  for (int l = 0; l < 8; ++l) {
    int f = t + (l << 9);
    int i = f >> 5, j = (f & 31) << 2;
    *(float4*)&a[i * 132 + j] = *(const float4*)(Sb + i * K_ + j);
  }
  __syncthreads();

  // ---- blocked GJ, 512 threads (round-5 structure): j=t&127, rr=t>>7 in [0,4)
  float* Pi = &Tl[0];        // 16x20
  float* Rp = &Tl[512];      // 16x132
  float* Cp = &Tl[4096];     // 128x20
  const int j = t & 127, rr = t >> 7;
  const int lane = t & 63;

  for (int p = 0; p < 8; ++p) {
    const int pb = p << 4;

    if (t < 64) {   // ph1: wave 0 inverts 16x16 pivot in registers
      const int r = lane & 15, g = lane >> 4;
      float4 v4 = *(const float4*)&a[(pb + r) * 132 + pb + (g << 2)];
      float vv[4] = {v4.x, v4.y, v4.z, v4.w};
#pragma unroll
      for (int k = 0; k < 16; ++k) {
        const int srcrow = (lane & 48) | k;
        float rk[4];
        rk[0] = __shfl(vv[0], srcrow);
        rk[1] = __shfl(vv[1], srcrow);
        rk[2] = __shfl(vv[2], srcrow);
        rk[3] = __shfl(vv[3], srcrow);
        const int kg = (k >> 2) << 4;
        const float pv = __shfl(vv[k & 3], kg | k);
        const float c  = __shfl(vv[k & 3], kg | r);
        const float pr = 1.0f / pv;
        float rs[4];
#pragma unroll
        for (int e = 0; e < 4; ++e) rs[e] = rk[e] * pr;
        if (r == k) {
#pragma unroll
          for (int e = 0; e < 4; ++e) vv[e] = rs[e];
          if (g == (k >> 2)) vv[k & 3] = pr;
        } else {
#pragma unroll
          for (int e = 0; e < 4; ++e) vv[e] = fmaf(-c, rs[e], vv[e]);
          if (g == (k >> 2)) vv[k & 3] = -c * pr;
        }
      }
      Pi[r * 20 + (g << 2) + 0] = vv[0];
      Pi[r * 20 + (g << 2) + 1] = vv[1];
      Pi[r * 20 + (g << 2) + 2] = vv[2];
      Pi[r * 20 + (g << 2) + 3] = vv[3];
    }
    __syncthreads();

    {  // ph2: Rp = Pinv @ A[p,:]; Cp = A[:,p]  (4 rows per group; float4 Cp)
      float Ak[16];
#pragma unroll
      for (int k = 0; k < 16; ++k) Ak[k] = a[(pb + k) * 132 + j];
      const unsigned jj = (unsigned)(j - pb);
      const int r0 = rr << 2;
#pragma unroll
      for (int q = 0; q < 4; ++q) {
        const int r = r0 + q;
        float acc = 0.f;
#pragma unroll
        for (int k = 0; k < 16; ++k) acc = fmaf(Pi[r * 20 + k], Ak[k], acc);
        Rp[r * 132 + j] = (jj < 16u) ? Pi[r * 20 + jj] : acc;
      }
      const int i = j;
      const int cb = rr << 2;
      float4 cA = *(const float4*)&a[i * 132 + pb + cb];
      *(float4*)&Cp[i * 20 + cb] = cA;
    }
    __syncthreads();

    {  // ph3: rank-16 update, 32 rows per group
      float Rk[16];
#pragma unroll
      for (int k = 0; k < 16; ++k) Rk[k] = Rp[k * 132 + j];
      const unsigned jj = (unsigned)(j - pb);
      const int i0 = rr << 5;
#pragma unroll 4
      for (int m = 0; m < 32; ++m) {
        const int i = i0 + m;
        const float4 c0 = *(const float4*)&Cp[i * 20];
        const float4 c1 = *(const float4*)&Cp[i * 20 + 4];
        const float4 c2 = *(const float4*)&Cp[i * 20 + 8];
        const float4 c3 = *(const float4*)&Cp[i * 20 + 12];
        float u0 = c0.x * Rk[0] + c0.y * Rk[1] + c0.z * Rk[2] + c0.w * Rk[3];
        float u1 = c1.x * Rk[4] + c1.y * Rk[5] + c1.z * Rk[6] + c1.w * Rk[7];
        float u2 = c2.x * Rk[8] + c2.y * Rk[9] + c2.z * Rk[10] + c2.w * Rk[11];
        float u3 = c3.x * Rk[12] + c3.y * Rk[13] + c3.z * Rk[14] + c3.w * Rk[15];
        const float upd = (u0 + u1) + (u2 + u3);
        const unsigned ii = (unsigned)(i - pb);
        float newv;
        if (ii < 16u) {
          newv = Rk[ii];
        } else {
          const float base = (jj < 16u) ? 0.f : a[i * 132 + j];
          newv = base - upd;
        }
        a[i * 132 + j] = newv;
      }
    }
    __syncthreads();
  }

  float* __restrict__ O = Sinv + (size_t)b * (K_ * K_);
#pragma unroll
  for (int l = 0; l < 8; ++l) {
    int f = t + (l << 9);
    int i = f >> 5, jq = (f & 31) << 2;
    *(float4*)(O + i * K_ + jq) = *(const float4*)&a[i * 132 + jq];
  }
}

// ---------------------------------------------------------------------------
// Kernel 5: ALL-3 Neumann iterations fused (row-local recurrence) --
// round-17 verbatim. 32 blocks x 256 thr; Sinv staged once into LDS.
// ---------------------------------------------------------------------------
__global__ __launch_bounds__(256)
void solve3(const float* __restrict__ Rm, const float* __restrict__ Sinv,
            const float* __restrict__ PQ, float* __restrict__ out) {
  const int bb = blockIdx.x;
  const int b = bb >> 2, rb = (bb & 3) << 5;
  const int t = threadIdx.x;
  __shared__ float Sv[K_ * 132];   // full Sinv, 67.6 KB
  __shared__ float Tnt[32 * 132];  // T rows (row-major), 16.9 KB
  __shared__ float q1[K_], p1[K_], q2l[32], p2l[32];

  {
    const float* P = PQ + b * 512;
    if (t < K_) { q1[t] = P[t]; p1[t] = P[128 + t]; }
    if (t < 32) { q2l[t] = P[256 + rb + t]; p2l[t] = P[384 + rb + t]; }
  }
  const float* __restrict__ Si = Sinv + (size_t)b * (K_ * K_);
#pragma unroll
  for (int l = 0; l < 16; ++l) {
    int f = t + (l << 8);
    int k = f >> 5, j4 = (f & 31) << 2;
    *(float4*)&Sv[k * 132 + j4] = *(const float4*)(Si + (size_t)k * K_ + j4);
  }

  const int ir = (t >> 4) << 1;        // local row pair (0..30)
  const int jc = (t & 15) << 3;        // 8-col group
  const float* __restrict__ Rb = Rm + (size_t)b * (K_ * K_);

  float R0[8], R1[8], X0r[8], X1r[8];
  {
    const int gi = rb + ir;
    float4 r00 = *(const float4*)(Rb + (size_t)gi * K_ + jc);
    float4 r01 = *(const float4*)(Rb + (size_t)gi * K_ + jc + 4);
    float4 r10 = *(const float4*)(Rb + (size_t)(gi + 1) * K_ + jc);
    float4 r11 = *(const float4*)(Rb + (size_t)(gi + 1) * K_ + jc + 4);
    R0[0]=r00.x; R0[1]=r00.y; R0[2]=r00.z; R0[3]=r00.w;
    R0[4]=r01.x; R0[5]=r01.y; R0[6]=r01.z; R0[7]=r01.w;
    R1[0]=r10.x; R1[1]=r10.y; R1[2]=r10.z; R1[3]=r10.w;
    R1[4]=r11.x; R1[5]=r11.y; R1[6]=r11.z; R1[7]=r11.w;
  }
  __syncthreads();   // Sv + pq ready

  const float q2i0 = q2l[ir],     p2i0 = p2l[ir];
  const float q2i1 = q2l[ir + 1], p2i1 = p2l[ir + 1];
  float q1j[8], p1j[8];
#pragma unroll
  for (int e = 0; e < 8; ++e) { q1j[e] = q1[jc + e]; p1j[e] = p1[jc + e]; }

  auto MATMUL = [&]() {
    float acc0[8] = {}, acc1[8] = {};
#pragma unroll 4
    for (int k = 0; k < K_; ++k) {
      const float a0 = Tnt[(ir + 0) * 132 + k];
      const float a1 = Tnt[(ir + 1) * 132 + k];
      const float4 b0 = *(const float4*)&Sv[k * 132 + jc];
      const float4 b1 = *(const float4*)&Sv[k * 132 + jc + 4];
      acc0[0] = fmaf(a0, b0.x, acc0[0]); acc0[1] = fmaf(a0, b0.y, acc0[1]);
      acc0[2] = fmaf(a0, b0.z, acc0[2]); acc0[3] = fmaf(a0, b0.w, acc0[3]);
      acc0[4] = fmaf(a0, b1.x, acc0[4]); acc0[5] = fmaf(a0, b1.y, acc0[5]);
      acc0[6] = fmaf(a0, b1.z, acc0[6]); acc0[7] = fmaf(a0, b1.w, acc0[7]);
      acc1[0] = fmaf(a1, b0.x, acc1[0]); acc1[1] = fmaf(a1, b0.y, acc1[1]);
      acc1[2] = fmaf(a1, b0.z, acc1[2]); acc1[3] = fmaf(a1, b0.w, acc1[3]);
      acc1[4] = fmaf(a1, b1.x, acc1[4]); acc1[5] = fmaf(a1, b1.y, acc1[5]);
      acc1[6] = fmaf(a1, b1.z, acc1[6]); acc1[7] = fmaf(a1, b1.w, acc1[7]);
    }
#pragma unroll
    for (int e = 0; e < 8; ++e) { X0r[e] = acc0[e]; X1r[e] = acc1[e]; }
  };

  // iter 1: T = R
#pragma unroll
  for (int e = 0; e < 8; ++e) {
    Tnt[(ir + 0) * 132 + jc + e] = R0[e];
    Tnt[(ir + 1) * 132 + jc + e] = R1[e];
  }
  __syncthreads();
  MATMUL();

  // iters 2,3: T = R - LMBDA*W.*X
#pragma unroll
  for (int itn = 0; itn < 2; ++itn) {
    __syncthreads();   // all matmul reads of Tnt done
#pragma unroll
    for (int e = 0; e < 8; ++e) {
      float dq = q2i0 - q1j[e], dp = p2i0 - p1j[e];
      float w = fmaf(dq, dq, dp * dp);
      Tnt[(ir + 0) * 132 + jc + e] = fmaf(-LMBDA * w, X0r[e], R0[e]);
      dq = q2i1 - q1j[e]; dp = p2i1 - p1j[e];
      w = fmaf(dq, dq, dp * dp);
      Tnt[(ir + 1) * 132 + jc + e] = fmaf(-LMBDA * w, X1r[e], R1[e]);
    }
    __syncthreads();
    MATMUL();
  }

  float* __restrict__ O = out + (size_t)b * (K_ * K_);
  const int gi = rb + ir;
  float4 o;
  o = (float4){X0r[0], X0r[1], X0r[2], X0r[3]}; *(float4*)(O + (size_t)gi * K_ + jc) = o;
  o = (float4){X0r[4], X0r[5], X0r[6], X0r[7]}; *(float4*)(O + (size_t)gi * K_ + jc + 4) = o;
  o = (float4){X1r[0], X1r[1], X1r[2], X1r[3]}; *(float4*)(O + (size_t)(gi + 1) * K_ + jc) = o;
  o = (float4){X1r[4], X1r[5], X1r[6], X1r[7]}; *(float4*)(O + (size_t)(gi + 1) * K_ + jc + 4) = o;
}

// ---------------------------------------------------------------------------
extern "C" void kernel_launch(void* const* d_in, const int* in_sizes, int n_in,
                              void* d_out, int out_size, void* d_ws, size_t ws_size,
                              hipStream_t stream) {
  (void)in_sizes; (void)n_in; (void)out_size;
  const float* feat_x  = (const float*)d_in[0];
  const float* feat_y  = (const float*)d_in[1];
  const float* evals_x = (const float*)d_in[2];
  const float* evals_y = (const float*)d_in[3];
  const float* evtx    = (const float*)d_in[4];
  const float* evty    = (const float*)d_in[5];
  float* out = (float*)d_out;
  float* ws  = (float*)d_ws;

  const size_t KC16 = (size_t)16 * K_ * C_;  // 524288 floats
  const size_t KK   = (size_t)K_ * K_;       // 16384
  const size_t fixed = KC16 + 3 * (KK * B_) + 4096;
  const int T = N_ / 32;  // 625 k-steps total

  // Sa=16 -> 512 blocks = 2/CU (best-measured proj config). Fallback 8.
  int Sa = ((16 * KC16 + fixed) * sizeof(float) <= ws_size) ? 16 : 8;
  int steps = (T + Sa - 1) / Sa;
  int chunk = steps * 32;
  Sa = (T + steps - 1) / steps;  // active slabs, all with nb < N_

  float* part = ws;
  float* AB   = part + (size_t)Sa * KC16;
  float* Sm   = AB + KC16;
  float* Rm   = Sm + KK * B_;
  float* Sinv = Rm + KK * B_;
  float* PQ   = Sinv + KK * B_;

  proj_mfma<<<dim3(Sa, 2, 16), 512, 0, stream>>>(feat_x, feat_y, evtx, evty, part, Sa, chunk);
  reduce_parts<<<dim3(16 * K_ * C_ / 4 / 256), 256, 0, stream>>>(part, AB, Sa);
  gram_kernel<<<dim3(8, 2, 4), 256, 0, stream>>>(AB, Sm, Rm);
  gjm_fused<<<dim3(8), 512, 0, stream>>>(Sm, evals_x, evals_y, Sinv, PQ);
  solve3<<<dim3(32), 256, 0, stream>>>(Rm, Sinv, PQ, out);
}

// Round 19
// 225.505 us; speedup vs baseline: 1.0514x; 1.0514x over previous
//
#include <hip/hip_runtime.h>
#include <math.h>

#define B_ 8
#define N_ 20000
#define K_ 128
#define C_ 256

static_assert(N_ % 32 == 0, "N must be multiple of 32");

constexpr float LMBDA = 100.0f;
constexpr float EPS_EV = 1e-10f;

typedef unsigned int u32x4 __attribute__((ext_vector_type(4)));
typedef short short8_t __attribute__((ext_vector_type(8)));
typedef float f32x4 __attribute__((ext_vector_type(4)));

// Split two fp32 into bf16 hi-plane (truncation; residual exact) and
// bf16 lo-plane (RNE of residual). Packed as (x1|x0) u32 words.
static __device__ inline void split2(float x0, float x1, unsigned& h, unsigned& l) {
  unsigned u0 = __builtin_bit_cast(unsigned, x0);
  unsigned u1 = __builtin_bit_cast(unsigned, x1);
  h = __builtin_amdgcn_perm(u1, u0, 0x07060302u);  // top16(x1)<<16 | top16(x0)
  float r0 = x0 - __builtin_bit_cast(float, u0 & 0xFFFF0000u);  // exact
  float r1 = x1 - __builtin_bit_cast(float, u1 & 0xFFFF0000u);  // exact
  unsigned v0 = __builtin_bit_cast(unsigned, r0);
  unsigned v1 = __builtin_bit_cast(unsigned, r1);
  v0 += 0x7FFFu + ((v0 >> 16) & 1u);  // RNE to bf16
  v1 += 0x7FFFu + ((v1 >> 16) & 1u);
  l = __builtin_amdgcn_perm(v1, v0, 0x07060302u);
}

// publish LDS writes + retire LDS reads, then raw barrier (global prefetch
// loads stay in flight across it -- no vmcnt drain).
#define KFENCE()                                              \
  do {                                                        \
    asm volatile("s_waitcnt lgkmcnt(0)" ::: "memory");        \
    __builtin_amdgcn_sched_barrier(0);                        \
    __builtin_amdgcn_s_barrier();                             \
    __builtin_amdgcn_sched_barrier(0);                        \
  } while (0)

// ---------------------------------------------------------------------------
// Kernel 1: projection GEMM, bf16x3 split MFMA (128x128 tile, fragment-linear
// LDS -> zero bank conflicts, KFENCE 2-phase, XCD grid). Session best.
// ---------------------------------------------------------------------------
__global__ __launch_bounds__(512, 4)
void proj_mfma(const float* __restrict__ feat_x, const float* __restrict__ feat_y,
               const float* __restrict__ evx, const float* __restrict__ evy,
               float* __restrict__ part, int Sa, int chunk) {
  const int bm = blockIdx.z;
  const int b = bm >> 1, mat = bm & 1;
  const float* __restrict__ E = (mat ? evy : evx) + (size_t)b * K_ * N_;
  const float* __restrict__ F = (mat ? feat_y : feat_x) + (size_t)b * N_ * C_;
  const int c0 = blockIdx.y << 7;          // y = c-block (swizzled)
  const int s = blockIdx.x;                // x = slab
  const int nb = s * chunk;
  const int ne = min(N_, nb + chunk);
  const int nt = (ne - nb) >> 5;

  // 64KB: buf p at p*8192 u32; planes: Ah +0, Al +2048, Bh +4096, Bl +6144
  __shared__ unsigned int LDSU[16384];

  const int t = threadIdx.x;
  const int lane = t & 63, wv = t >> 6;
  const int wm = wv & 3;          // m-tile 0..3 (32 rows each)
  const int wcc = wv >> 2;        // c-half 0..1 (64 cols each)
  const int lr = lane & 15, lg = lane >> 4;

  // staging maps (slot t, fragment-linear)
  const int rA = ((t >> 7) << 5) | (((t >> 6) & 1) << 4) | (t & 15);
  const int oA = (t >> 4) & 3;
  const int cB = ((t >> 6) << 4) | (t & 15);
  const int oB = (t >> 4) & 3;

  const float* __restrict__ eb = E + (size_t)rA * N_ + (oA << 3);
  const float* __restrict__ fb = F + (size_t)(oB << 3) * C_ + c0 + cB;

  f32x4 acc[2][4];
#pragma unroll
  for (int i = 0; i < 2; ++i)
#pragma unroll
    for (int j = 0; j < 4; ++j) acc[i][j] = (f32x4){0.f, 0.f, 0.f, 0.f};

  struct Stage { float4 a0, a1; float b0, b1, b2, b3, b4, b5, b6, b7; };

  auto LOAD = [&](Stage& st, int n0) {
    const float* ep = eb + n0;
    st.a0 = *(const float4*)ep;
    st.a1 = *(const float4*)(ep + 4);
    const float* fp = fb + (size_t)n0 * C_;
    st.b0 = fp[0];
    st.b1 = fp[C_];
    st.b2 = fp[2 * C_];
    st.b3 = fp[3 * C_];
    st.b4 = fp[4 * C_];
    st.b5 = fp[5 * C_];
    st.b6 = fp[6 * C_];
    st.b7 = fp[7 * C_];
  };

  auto WRITE = [&](Stage& st, int p) {
    const int base = (p << 13) + (t << 2);
    unsigned h0, l0, h1, l1, h2, l2, h3, l3;
    split2(st.a0.x, st.a0.y, h0, l0);
    split2(st.a0.z, st.a0.w, h1, l1);
    split2(st.a1.x, st.a1.y, h2, l2);
    split2(st.a1.z, st.a1.w, h3, l3);
    *(u32x4*)&LDSU[base]        = (u32x4){h0, h1, h2, h3};
    *(u32x4*)&LDSU[base + 2048] = (u32x4){l0, l1, l2, l3};
    split2(st.b0, st.b1, h0, l0);
    split2(st.b2, st.b3, h1, l1);
    split2(st.b4, st.b5, h2, l2);
    split2(st.b6, st.b7, h3, l3);
    *(u32x4*)&LDSU[base + 4096] = (u32x4){h0, h1, h2, h3};
    *(u32x4*)&LDSU[base + 6144] = (u32x4){l0, l1, l2, l3};
  };

  auto COMPUTE = [&](int p) {
    const int pb = p << 13;
    short8_t a_h[2], a_l[2];
#pragma unroll
    for (int mt = 0; mt < 2; ++mt) {
      const int as = pb + (((wm << 1) + mt) << 8) + (lane << 2);
      a_h[mt] = *(const short8_t*)&LDSU[as];
      a_l[mt] = *(const short8_t*)&LDSU[as + 2048];
    }
#pragma unroll
    for (int ct = 0; ct < 4; ++ct) {
      const int ctg = (wcc << 2) + ct;
      const int bs = pb + 4096 + (ctg << 8) + (lane << 2);
      const short8_t b_h = *(const short8_t*)&LDSU[bs];
      const short8_t b_l = *(const short8_t*)&LDSU[bs + 2048];
#pragma unroll
      for (int mt = 0; mt < 2; ++mt) {
        acc[mt][ct] = __builtin_amdgcn_mfma_f32_16x16x32_bf16(a_h[mt], b_h, acc[mt][ct], 0, 0, 0);
        acc[mt][ct] = __builtin_amdgcn_mfma_f32_16x16x32_bf16(a_l[mt], b_h, acc[mt][ct], 0, 0, 0);
        acc[mt][ct] = __builtin_amdgcn_mfma_f32_16x16x32_bf16(a_h[mt], b_l, acc[mt][ct], 0, 0, 0);
      }
    }
  };

  Stage sA, sB;
  LOAD(sA, nb);                       // tile 0
  if (nt > 1) LOAD(sB, nb + 32);      // tile 1
  WRITE(sA, 0);                       // waits only tile-0 loads
  KFENCE();

  for (int it = 0; it < nt; it += 2) {
    if (it + 1 < nt) WRITE(sB, 1);                    // vmcnt wait: tile it+1
    if (it + 2 < nt) LOAD(sA, nb + ((it + 2) << 5));  // issued AFTER the wait
    COMPUTE(0);
    KFENCE();
    if (it + 1 < nt) {
      if (it + 2 < nt) WRITE(sA, 0);
      if (it + 3 < nt) LOAD(sB, nb + ((it + 3) << 5));
      COMPUTE(1);
      KFENCE();
    }
  }

  // epilogue: C/D layout col=lane&15, row=(lane>>4)*4+r
  float* __restrict__ P = part + ((size_t)bm * Sa + s) * (K_ * C_);
#pragma unroll
  for (int mt = 0; mt < 2; ++mt)
#pragma unroll
    for (int ct = 0; ct < 4; ++ct) {
      const int ccol = c0 + (wcc << 6) + (ct << 4) + lr;
#pragma unroll
      for (int r = 0; r < 4; ++r) {
        const int mrow = (wm << 5) + (mt << 4) + (lg << 2) + r;
        P[(size_t)mrow * C_ + ccol] = acc[mt][ct][r];
      }
    }
}

// ---------------------------------------------------------------------------
// Kernel 2: reduce split-n partials -> AB (float4 vectorized)
// ---------------------------------------------------------------------------
__global__ void reduce_parts(const float* __restrict__ part, float* __restrict__ AB, int Sa) {
  const int idx4 = blockIdx.x * 256 + threadIdx.x;       // float4 units
  if (idx4 >= 16 * K_ * C_ / 4) return;
  const int per = K_ * C_ / 4;
  const int bm = idx4 / per;
  const int rem4 = idx4 - bm * per;
  float4 v = {0.f, 0.f, 0.f, 0.f};
  for (int s = 0; s < Sa; ++s) {
    const float4 p = *(const float4*)&part[((size_t)bm * Sa + s) * (K_ * C_) + rem4 * 4];
    v.x += p.x; v.y += p.y; v.z += p.z; v.w += p.w;
  }
  *(float4*)&AB[(size_t)idx4 * 4] = v;
}

// ---------------------------------------------------------------------------
// Kernel 3: gram matrices, 64x64 quadrant per block (8 x 2 x 4 grid).
// which=0: Sm = A A^T + 1e-8 I ; which=1: Rm = Bm A^T
// ---------------------------------------------------------------------------
__global__ __launch_bounds__(256)
void gram_kernel(const float* __restrict__ AB, float* __restrict__ Sm, float* __restrict__ Rm) {
  const int b = blockIdx.x, which = blockIdx.y, qz = blockIdx.z;
  const int iq = (qz & 1) << 6, jq = (qz >> 1) << 6;
  const float* __restrict__ L  = AB + ((size_t)(b * 2 + which)) * (K_ * C_);
  const float* __restrict__ Ar = AB + ((size_t)(b * 2)) * (K_ * C_);
  float* __restrict__ out = (which ? Rm : Sm) + (size_t)b * (K_ * K_);
  const int t = threadIdx.x;
  const int ir = iq + ((t >> 4) << 2), jc = jq + ((t & 15) << 2);
  float acc[4][4] = {};
  for (int c0 = 0; c0 < C_; c0 += 4) {
    float4 li[4], rj[4];
#pragma unroll
    for (int i = 0; i < 4; ++i) li[i] = *(const float4*)(L + (size_t)(ir + i) * C_ + c0);
#pragma unroll
    for (int j = 0; j < 4; ++j) rj[j] = *(const float4*)(Ar + (size_t)(jc + j) * C_ + c0);
#pragma unroll
    for (int i = 0; i < 4; ++i)
#pragma unroll
      for (int j = 0; j < 4; ++j)
        acc[i][j] += li[i].x * rj[j].x + li[i].y * rj[j].y +
                     li[i].z * rj[j].z + li[i].w * rj[j].w;
  }
#pragma unroll
  for (int i = 0; i < 4; ++i)
#pragma unroll
    for (int j = 0; j < 4; ++j) {
      float v = acc[i][j];
      if (!which && (ir + i) == (jc + j)) v += 1e-8f;
      out[(size_t)(ir + i) * K_ + (jc + j)] = v;
    }
}

// ---------------------------------------------------------------------------
// Kernel 4: FUSED mask-prep + blocked Gauss-Jordan inverse (1024 threads,
// round-17 measured-best).
// ---------------------------------------------------------------------------
__global__ __launch_bounds__(1024)
void gjm_fused(const float* __restrict__ Sm, const float* __restrict__ evx,
               const float* __restrict__ evy, float* __restrict__ Sinv,
               float* __restrict__ PQ) {
  const int b = blockIdx.x, t = threadIdx.x;
  __shared__ float a[K_ * 132];    // S -> Sinv
  __shared__ float Tl[K_ * 132];   // gj scratch
  __shared__ float ev[256];
  __shared__ float wmax[2];

  if (t < 128) {
    float e1 = evx[b * K_ + t];
    float e2 = evy[b * K_ + t];
    if (e1 != e1) e1 = EPS_EV;
    if (e2 != e2) e2 = EPS_EV;
    e1 = fminf(fmaxf(e1, EPS_EV), 1e6f);
    e2 = fminf(fmaxf(e2, EPS_EV), 1e6f);
    float v = fmaxf(e1, e2);
#pragma unroll
    for (int d = 1; d < 64; d <<= 1) v = fmaxf(v, __shfl_xor(v, d, 64));
    if ((t & 63) == 0) wmax[t >> 6] = v;
    ev[t] = e1; ev[128 + t] = e2;
  }
  __syncthreads();
  if (t < 128) {
    const float scale = fmaxf(fmaxf(wmax[0], wmax[1]), 1e-10f);
    const float g1 = sqrtf(ev[t] / scale);
    const float g2 = sqrtf(ev[128 + t] / scale);
    const float d1 = fmaf(g1, g1, 1.f);
    const float d2 = fmaf(g2, g2, 1.f);
    float* P = PQ + b * 512;
    P[t]       = g1 / d1;
    P[128 + t] = 1.f / d1;
    P[256 + t] = g2 / d2;
    P[384 + t] = 1.f / d2;
  }

  const float* __restrict__ Sb = Sm + (size_t)b * (K_ * K_);
#pragma unroll
  for (int l = 0; l < 4; ++l) {
    int f = t + (l << 10);
    int i = f >> 5, j = (f & 31) << 2;
    *(float4*)&a[i * 132 + j] = *(const float4*)(Sb + i * K_ + j);
  }
  __syncthreads();

  float* Pi = &Tl[0];
  float* Rp = &Tl[512];
  float* Cp = &Tl[4096];
  const int j = t & 127, rr = t >> 7;
  const int lane = t & 63;

  for (int p = 0; p < 8; ++p) {
    const int pb = p << 4;

    if (t < 64) {   // ph1: wave 0 inverts 16x16 pivot in registers
      const int r = lane & 15, g = lane >> 4;
      float4 v4 = *(const float4*)&a[(pb + r) * 132 + pb + (g << 2)];
      float vv[4] = {v4.x, v4.y, v4.z, v4.w};
#pragma unroll
      for (int k = 0; k < 16; ++k) {
        const int srcrow = (lane & 48) | k;
        float rk[4];
        rk[0] = __shfl(vv[0], srcrow);
        rk[1] = __shfl(vv[1], srcrow);
        rk[2] = __shfl(vv[2], srcrow);
        rk[3] = __shfl(vv[3], srcrow);
        const int kg = (k >> 2) << 4;
        const float pv = __shfl(vv[k & 3], kg | k);
        const float c  = __shfl(vv[k & 3], kg | r);
        const float pr = 1.0f / pv;
        float rs[4];
#pragma unroll
        for (int e = 0; e < 4; ++e) rs[e] = rk[e] * pr;
        if (r == k) {
#pragma unroll
          for (int e = 0; e < 4; ++e) vv[e] = rs[e];
          if (g == (k >> 2)) vv[k & 3] = pr;
        } else {
#pragma unroll
          for (int e = 0; e < 4; ++e) vv[e] = fmaf(-c, rs[e], vv[e]);
          if (g == (k >> 2)) vv[k & 3] = -c * pr;
        }
      }
      Pi[r * 20 + (g << 2) + 0] = vv[0];
      Pi[r * 20 + (g << 2) + 1] = vv[1];
      Pi[r * 20 + (g << 2) + 2] = vv[2];
      Pi[r * 20 + (g << 2) + 3] = vv[3];
    }
    __syncthreads();

    {  // ph2: Rp = Pinv @ A[p,:]; Cp = A[:,p]
      float Ak[16];
#pragma unroll
      for (int k = 0; k < 16; ++k) Ak[k] = a[(pb + k) * 132 + j];
      const unsigned jj = (unsigned)(j - pb);
#pragma unroll
      for (int q = 0; q < 2; ++q) {
        const int r = (rr << 1) + q;
        float acc = 0.f;
#pragma unroll
        for (int k = 0; k < 16; ++k) acc = fmaf(Pi[r * 20 + k], Ak[k], acc);
        Rp[r * 132 + j] = (jj < 16u) ? Pi[r * 20 + jj] : acc;
      }
      const int i = j;
      const int cb = rr << 1;
      float2 cA = *(const float2*)&a[i * 132 + pb + cb];
      *(float2*)&Cp[i * 20 + cb] = cA;
    }
    __syncthreads();

    {  // ph3: rank-16 update, 16 rows per group
      float Rk[16];
#pragma unroll
      for (int k = 0; k < 16; ++k) Rk[k] = Rp[k * 132 + j];
      const unsigned jj = (unsigned)(j - pb);
      const int i0 = rr << 4;
#pragma unroll 4
      for (int m = 0; m < 16; ++m) {
        const int i = i0 + m;
        const float4 c0 = *(const float4*)&Cp[i * 20];
        const float4 c1 = *(const float4*)&Cp[i * 20 + 4];
        const float4 c2 = *(const float4*)&Cp[i * 20 + 8];
        const float4 c3 = *(const float4*)&Cp[i * 20 + 12];
        float u0 = c0.x * Rk[0] + c0.y * Rk[1] + c0.z * Rk[2] + c0.w * Rk[3];
        float u1 = c1.x * Rk[4] + c1.y * Rk[5] + c1.z * Rk[6] + c1.w * Rk[7];
        float u2 = c2.x * Rk[8] + c2.y * Rk[9] + c2.z * Rk[10] + c2.w * Rk[11];
        float u3 = c3.x * Rk[12] + c3.y * Rk[13] + c3.z * Rk[14] + c3.w * Rk[15];
        const float upd = (u0 + u1) + (u2 + u3);
        const unsigned ii = (unsigned)(i - pb);
        float newv;
        if (ii < 16u) {
          newv = Rk[ii];
        } else {
          const float base = (jj < 16u) ? 0.f : a[i * 132 + j];
          newv = base - upd;
        }
        a[i * 132 + j] = newv;
      }
    }
    __syncthreads();
  }

  float* __restrict__ O = Sinv + (size_t)b * (K_ * K_);
#pragma unroll
  for (int l = 0; l < 4; ++l) {
    int f = t + (l << 10);
    int i = f >> 5, jq = (f & 31) << 2;
    *(float4*)(O + i * K_ + jq) = *(const float4*)&a[i * 132 + jq];
  }
}

// ---------------------------------------------------------------------------
// Kernel 5: ALL-3 Neumann iterations fused (row-local recurrence) --
// round-17 verbatim. 32 blocks x 256 thr; Sinv staged once into LDS.
// ---------------------------------------------------------------------------
__global__ __launch_bounds__(256)
void solve3(const float* __restrict__ Rm, const float* __restrict__ Sinv,
            const float* __restrict__ PQ, float* __restrict__ out) {
  const int bb = blockIdx.x;
  const int b = bb >> 2, rb = (bb & 3) << 5;
  const int t = threadIdx.x;
  __shared__ float Sv[K_ * 132];   // full Sinv, 67.6 KB
  __shared__ float Tnt[32 * 132];  // T rows (row-major), 16.9 KB
  __shared__ float q1[K_], p1[K_], q2l[32], p2l[32];

  {
    const float* P = PQ + b * 512;
    if (t < K_) { q1[t] = P[t]; p1[t] = P[128 + t]; }
    if (t < 32) { q2l[t] = P[256 + rb + t]; p2l[t] = P[384 + rb + t]; }
  }
  const float* __restrict__ Si = Sinv + (size_t)b * (K_ * K_);
#pragma unroll
  for (int l = 0; l < 16; ++l) {
    int f = t + (l << 8);
    int k = f >> 5, j4 = (f & 31) << 2;
    *(float4*)&Sv[k * 132 + j4] = *(const float4*)(Si + (size_t)k * K_ + j4);
  }

  const int ir = (t >> 4) << 1;        // local row pair (0..30)
  const int jc = (t & 15) << 3;        // 8-col group
  const float* __restrict__ Rb = Rm + (size_t)b * (K_ * K_);

  float R0[8], R1[8], X0r[8], X1r[8];
  {
    const int gi = rb + ir;
    float4 r00 = *(const float4*)(Rb + (size_t)gi * K_ + jc);
    float4 r01 = *(const float4*)(Rb + (size_t)gi * K_ + jc + 4);
    float4 r10 = *(const float4*)(Rb + (size_t)(gi + 1) * K_ + jc);
    float4 r11 = *(const float4*)(Rb + (size_t)(gi + 1) * K_ + jc + 4);
    R0[0]=r00.x; R0[1]=r00.y; R0[2]=r00.z; R0[3]=r00.w;
    R0[4]=r01.x; R0[5]=r01.y; R0[6]=r01.z; R0[7]=r01.w;
    R1[0]=r10.x; R1[1]=r10.y; R1[2]=r10.z; R1[3]=r10.w;
    R1[4]=r11.x; R1[5]=r11.y; R1[6]=r11.z; R1[7]=r11.w;
  }
  __syncthreads();   // Sv + pq ready

  const float q2i0 = q2l[ir],     p2i0 = p2l[ir];
  const float q2i1 = q2l[ir + 1], p2i1 = p2l[ir + 1];
  float q1j[8], p1j[8];
#pragma unroll
  for (int e = 0; e < 8; ++e) { q1j[e] = q1[jc + e]; p1j[e] = p1[jc + e]; }

  auto MATMUL = [&]() {
    float acc0[8] = {}, acc1[8] = {};
#pragma unroll 4
    for (int k = 0; k < K_; ++k) {
      const float a0 = Tnt[(ir + 0) * 132 + k];
      const float a1 = Tnt[(ir + 1) * 132 + k];
      const float4 b0 = *(const float4*)&Sv[k * 132 + jc];
      const float4 b1 = *(const float4*)&Sv[k * 132 + jc + 4];
      acc0[0] = fmaf(a0, b0.x, acc0[0]); acc0[1] = fmaf(a0, b0.y, acc0[1]);
      acc0[2] = fmaf(a0, b0.z, acc0[2]); acc0[3] = fmaf(a0, b0.w, acc0[3]);
      acc0[4] = fmaf(a0, b1.x, acc0[4]); acc0[5] = fmaf(a0, b1.y, acc0[5]);
      acc0[6] = fmaf(a0, b1.z, acc0[6]); acc0[7] = fmaf(a0, b1.w, acc0[7]);
      acc1[0] = fmaf(a1, b0.x, acc1[0]); acc1[1] = fmaf(a1, b0.y, acc1[1]);
      acc1[2] = fmaf(a1, b0.z, acc1[2]); acc1[3] = fmaf(a1, b0.w, acc1[3]);
      acc1[4] = fmaf(a1, b1.x, acc1[4]); acc1[5] = fmaf(a1, b1.y, acc1[5]);
      acc1[6] = fmaf(a1, b1.z, acc1[6]); acc1[7] = fmaf(a1, b1.w, acc1[7]);
    }
#pragma unroll
    for (int e = 0; e < 8; ++e) { X0r[e] = acc0[e]; X1r[e] = acc1[e]; }
  };

  // iter 1: T = R
#pragma unroll
  for (int e = 0; e < 8; ++e) {
    Tnt[(ir + 0) * 132 + jc + e] = R0[e];
    Tnt[(ir + 1) * 132 + jc + e] = R1[e];
  }
  __syncthreads();
  MATMUL();

  // iters 2,3: T = R - LMBDA*W.*X
#pragma unroll
  for (int itn = 0; itn < 2; ++itn) {
    __syncthreads();   // all matmul reads of Tnt done
#pragma unroll
    for (int e = 0; e < 8; ++e) {
      float dq = q2i0 - q1j[e], dp = p2i0 - p1j[e];
      float w = fmaf(dq, dq, dp * dp);
      Tnt[(ir + 0) * 132 + jc + e] = fmaf(-LMBDA * w, X0r[e], R0[e]);
      dq = q2i1 - q1j[e]; dp = p2i1 - p1j[e];
      w = fmaf(dq, dq, dp * dp);
      Tnt[(ir + 1) * 132 + jc + e] = fmaf(-LMBDA * w, X1r[e], R1[e]);
    }
    __syncthreads();
    MATMUL();
  }

  float* __restrict__ O = out + (size_t)b * (K_ * K_);
  const int gi = rb + ir;
  float4 o;
  o = (float4){X0r[0], X0r[1], X0r[2], X0r[3]}; *(float4*)(O + (size_t)gi * K_ + jc) = o;
  o = (float4){X0r[4], X0r[5], X0r[6], X0r[7]}; *(float4*)(O + (size_t)gi * K_ + jc + 4) = o;
  o = (float4){X1r[0], X1r[1], X1r[2], X1r[3]}; *(float4*)(O + (size_t)(gi + 1) * K_ + jc) = o;
  o = (float4){X1r[4], X1r[5], X1r[6], X1r[7]}; *(float4*)(O + (size_t)(gi + 1) * K_ + jc + 4) = o;
}

// ---------------------------------------------------------------------------
extern "C" void kernel_launch(void* const* d_in, const int* in_sizes, int n_in,
                              void* d_out, int out_size, void* d_ws, size_t ws_size,
                              hipStream_t stream) {
  (void)in_sizes; (void)n_in; (void)out_size;
  const float* feat_x  = (const float*)d_in[0];
  const float* feat_y  = (const float*)d_in[1];
  const float* evals_x = (const float*)d_in[2];
  const float* evals_y = (const float*)d_in[3];
  const float* evtx    = (const float*)d_in[4];
  const float* evty    = (const float*)d_in[5];
  float* out = (float*)d_out;
  float* ws  = (float*)d_ws;

  const size_t KC16 = (size_t)16 * K_ * C_;  // 524288 floats
  const size_t KK   = (size_t)K_ * K_;       // 16384
  const size_t fixed = KC16 + 3 * (KK * B_) + 4096;
  const int T = N_ / 32;  // 625 k-steps total

  // Sa=16 -> 512 blocks = 2/CU (best-measured proj config). Fallback 8.
  int Sa = ((16 * KC16 + fixed) * sizeof(float) <= ws_size) ? 16 : 8;
  int steps = (T + Sa - 1) / Sa;
  int chunk = steps * 32;
  Sa = (T + steps - 1) / steps;  // active slabs, all with nb < N_

  float* part = ws;
  float* AB   = part + (size_t)Sa * KC16;
  float* Sm   = AB + KC16;
  float* Rm   = Sm + KK * B_;
  float* Sinv = Rm + KK * B_;
  float* PQ   = Sinv + KK * B_;

  proj_mfma<<<dim3(Sa, 2, 16), 512, 0, stream>>>(feat_x, feat_y, evtx, evty, part, Sa, chunk);
  reduce_parts<<<dim3(16 * K_ * C_ / 4 / 256), 256, 0, stream>>>(part, AB, Sa);
  gram_kernel<<<dim3(8, 2, 4), 256, 0, stream>>>(AB, Sm, Rm);
  gjm_fused<<<dim3(8), 1024, 0, stream>>>(Sm, evals_x, evals_y, Sinv, PQ);
  solve3<<<dim3(32), 256, 0, stream>>>(Rm, Sinv, PQ, out);
}